// Round 13
// baseline (166.619 us; speedup 1.0000x reference)
//
#include <hip/hip_runtime.h>
#include <hip/hip_bf16.h>
#include <math.h>

#define N_IN 85680
#define PRE_K 5000
#define POST_K 750
#define NW 79            // ceil(PRE_K/64) words
#define NPAD 5056        // NW*64
#define HSIZE 8192       // linear buckets over score-bit range (0.02, +inf)
#define CAND_MAX 8192
#define CONF_THR 0.02f
#define NMS_THR 0.4f
#define BITS_THR 0x3CA3D70Bu  // bits of smallest float > 0.02f

typedef unsigned int u32;
typedef unsigned long long u64;

// column-major triangle-packed mask: word k's segment starts at cbase(k), holds
// rows 64k..NPAD-1. cbase(k) = k*(5088 - 32k)  [u64 units]; cbase(79)=202240.
__device__ __forceinline__ int cbase(int k) { return k * (5088 - 32 * k); }

// opacity barrier: prevents FMA contraction so f32 math bit-matches numpy ref
__device__ __forceinline__ float opaquef(float x) { asm volatile("" : "+v"(x)); return x; }

// wave-uniform 64-bit broadcast via v_readlane (src lane must be uniform)
__device__ __forceinline__ u64 readlane64(u64 v, int l) {
    u32 lo = __builtin_amdgcn_readlane((u32)v, l);
    u32 hi = __builtin_amdgcn_readlane((u32)(v >> 32), l);
    return ((u64)hi << 32) | (u64)lo;
}

// monotone bucket of a score's float bits (score > CONF_THR guaranteed)
__device__ __forceinline__ u32 bucket_of(u32 bits) {
    u32 b = (bits - BITS_THR) >> 13;
    return b >= HSIZE ? (HSIZE - 1) : b;
}

// ---------------- fused histogram + suffix-scan (1 block); also zeroes bfill/validm ----------------
__global__ __launch_bounds__(1024) void histscan_kernel(const float2* __restrict__ conf2,
                                                        u32* __restrict__ bsel,
                                                        u32* __restrict__ bstart,
                                                        u32* __restrict__ bfill,
                                                        u64* __restrict__ validm) {
    __shared__ u32 h[HSIZE];
    __shared__ u32 tot[1024];
    int c = threadIdx.x;
    for (int b = c; b < HSIZE; b += 1024) h[b] = 0u;
    __syncthreads();
    for (int i = c; i < N_IN; i += 1024) {
        float s = conf2[i].y;
        if (s > CONF_THR) atomicAdd(&h[bucket_of(__float_as_uint(s))], 1u);
    }
    __syncthreads();
    u32 lh[8];
    u32 t = 0;
#pragma unroll
    for (int k = 0; k < 8; ++k) { lh[k] = h[c * 8 + k]; t += lh[k]; }
    tot[c] = t;
    __syncthreads();
    for (int d = 1; d < 1024; d <<= 1) {
        u32 v = tot[c] + ((c + d < 1024) ? tot[c + d] : 0u);
        __syncthreads();
        tot[c] = v;
        __syncthreads();
    }
    u32 above = (c + 1 < 1024) ? tot[c + 1] : 0u;
    u32 s = above;
    for (int k = 7; k >= 0; --k) { bstart[c * 8 + k] = s; s += lh[k]; }
    if (above < PRE_K && above + t >= PRE_K) {
        u32 cum = above;
        for (int k = 7; k >= 0; --k) {
            cum += lh[k];
            if (cum >= PRE_K) { bsel[0] = (u32)(c * 8 + k); break; }
        }
    }
    if (c == 0 && tot[0] < PRE_K) bsel[0] = 0u;
    for (int b = c; b < HSIZE; b += 1024) bfill[b] = 0u;
    if (c < 128) validm[c] = 0ull;
}

// ---------------- scatter candidates bucket-grouped ----------------
__global__ __launch_bounds__(256) void compact_kernel(const float2* __restrict__ conf2,
                                                      const u32* __restrict__ bsel,
                                                      const u32* __restrict__ bstart,
                                                      u32* __restrict__ bfill,
                                                      u64* __restrict__ cand) {
    int i = blockIdx.x * 256 + threadIdx.x;
    if (i >= N_IN) return;
    float sc = conf2[i].y;
    if (!(sc > CONF_THR)) return;
    u32 bits = __float_as_uint(sc);
    u32 b = bucket_of(bits);
    if (b < bsel[0]) return;
    u32 pos = bstart[b] + atomicAdd(&bfill[b], 1u);
    if (pos < CAND_MAX) cand[pos] = ((u64)bits << 32) | (u64)(u32)(~(u32)i);
}

// ---------------- fused: exact rank within bucket + decode -> rows/boxes/validm ----------------
__global__ __launch_bounds__(256) void rankdec_kernel(const u64* __restrict__ cand,
                                                      const u32* __restrict__ bstart,
                                                      const u32* __restrict__ bfill,
                                                      const u32* __restrict__ bsel,
                                                      const float4* __restrict__ loc4,
                                                      const float4* __restrict__ pri4,
                                                      const float* __restrict__ lmk,
                                                      const int* __restrict__ imw,
                                                      const int* __restrict__ imh,
                                                      float4* __restrict__ rows4,
                                                      float4* __restrict__ boxes,
                                                      u64* __restrict__ validm) {
    u32 bs = bsel[0];
    u32 total = bstart[bs] + bfill[bs];
    if (total > CAND_MAX) total = CAND_MAX;
    float W = (float)(*imw), H = (float)(*imh);
    for (u32 s = blockIdx.x * blockDim.x + threadIdx.x; s < total;
         s += gridDim.x * blockDim.x) {
        u64 key = cand[s];
        u32 b = bucket_of((u32)(key >> 32));
        u32 st = bstart[b];
        u32 en = st + bfill[b];
        if (en > CAND_MAX) en = CAND_MAX;
        u32 r = st;
        for (u32 j = st; j < en; ++j) r += (cand[j] > key) ? 1u : 0u;
        if (r >= PRE_K) continue;
        u32 i = ~(u32)key;
        float score = __uint_as_float((u32)(key >> 32));
        float4 L = loc4[i];
        float4 P = pri4[i];
        float cx = P.x + opaquef((L.x * 0.1f) * P.z);
        float cy = P.y + opaquef((L.y * 0.1f) * P.w);
        float bw = P.z * (float)exp((double)(L.z * 0.2f));
        float bh = P.w * (float)exp((double)(L.w * 0.2f));
        float hw = opaquef(bw * 0.5f), hh = opaquef(bh * 0.5f);
        float x0 = (cx - hw) * W, y0 = (cy - hh) * H;
        float x1 = (cx + hw) * W, y1 = (cy + hh) * H;
        boxes[r] = make_float4(x0, y0, x1, y1);
        float lm[10];
#pragma unroll
        for (int p = 0; p < 5; ++p) {
            float2 q = ((const float2*)lmk)[(size_t)i * 5 + p];
            lm[2 * p]     = (P.x + opaquef((q.x * 0.1f) * P.z)) * W;
            lm[2 * p + 1] = (P.y + opaquef((q.y * 0.1f) * P.w)) * H;
        }
        float4* row = rows4 + (size_t)r * 4;
        row[0] = make_float4(x0, y0, x1, y1);
        row[1] = make_float4(score, lm[0], lm[1], lm[2]);
        row[2] = make_float4(lm[3], lm[4], lm[5], lm[6]);
        row[3] = make_float4(lm[7], lm[8], lm[9], 0.f);
        atomicOr(&validm[r >> 6], 1ull << (r & 63));
    }
}

// ---------------- symmetric IoU bitmask, column-major triangle-packed ----------------
__global__ __launch_bounds__(64) void mask_kernel(const float4* __restrict__ boxes,
                                                  u64* __restrict__ cmask) {
    int rem = blockIdx.x, rc = 0;
    while (rem >= rc + 1) { rem -= rc + 1; ++rc; }
    int cc = rem;
    __shared__ float4 cb[64];
    int t = threadIdx.x;
    cb[t] = boxes[cc * 64 + t];
    int i = rc * 64 + t;
    float4 bi = boxes[i];
    __syncthreads();
    float areai = (bi.z - bi.x) * (bi.w - bi.y);
    u64 word = 0ull;
#pragma unroll 4
    for (int k = 0; k < 64; ++k) {
        float4 bj = cb[k];
        float areaj = (bj.z - bj.x) * (bj.w - bj.y);
        float ltx = fmaxf(bi.x, bj.x), lty = fmaxf(bi.y, bj.y);
        float rbx = fminf(bi.z, bj.z), rby = fminf(bi.w, bj.w);
        float wx = fmaxf(rbx - ltx, 0.f), wy = fmaxf(rby - lty, 0.f);
        float inter = opaquef(wx * wy);
        float uni = fmaxf(areai + areaj - inter, 1e-12f);
        float iou = inter / uni;
        if (iou > NMS_THR) word |= (1ull << k);
    }
    if (i < PRE_K) cmask[(size_t)(cbase(cc) + (i - 64 * cc))] = word;
}

// ---------------- exact one-pass Gauss-Seidel NMS + fused scatter (1 block, 16 waves) ----
// Words solve strictly in index order (GS in topological order == greedy fixpoint,
// ONE pass). Word w owned by wave w%16; LDS doneCnt release/acquire handshake.
// While waiting, a wave pre-folds sup over already-final predecessor words.
// R12 BUG FIX: dreg must be UNMASKED — readlane64(dreg,b) = row b of the symmetric
// block = "whom b suppresses" (bits > b needed). Masking below-lane deleted them.
// Low bits of row b are harmless in the chain: when b = ffs(cur), no bits < b
// remain in cur; the self-bit is OR'd explicitly.
__global__ __launch_bounds__(1024) void reduce_scatter_kernel(const u64* __restrict__ cmask,
                                                              const u64* __restrict__ validm,
                                                              const float* __restrict__ rows,
                                                              float* __restrict__ out) {
    int tid = threadIdx.x;
    int g = tid >> 6, lane = tid & 63;
    __shared__ u64 keepAll[96];
    __shared__ u32 doneCnt;   // number of finalized words (or sentinel NW+9)
    __shared__ u32 totK;
    __shared__ u32 wpref[96];
    for (int k = tid; k < 96; k += 1024) keepAll[k] = 0ull;
    if (tid == 0) { doneCnt = 0u; totK = 0u; }
    __syncthreads();

    for (int s = 0; s < 5; ++s) {
        int w = s * 16 + g;
        if (w >= NW) break;
        int r = 64 * w + lane;
        // diag word (row r, word w) — UNMASKED (see header comment)
        u64 dreg = cmask[(size_t)(cbase(w) + lane)];
        // preload last two predecessors' column data (independent of keep state)
        u64 dA = 0ull, dB = 0ull;
        if (w >= 1) dA = cmask[(size_t)(cbase(w - 1) + r - 64 * (w - 1))];
        if (w >= 2) dB = cmask[(size_t)(cbase(w - 2) + r - 64 * (w - 2))];
        int wcap = (w >= 2) ? (w - 2) : 0;
        u64 sup = 0ull;
        u32 d0 = 0;
        u32 d = __hip_atomic_load(&doneCnt, __ATOMIC_ACQUIRE, __HIP_MEMORY_SCOPE_WORKGROUP);
        for (;;) {
            u32 lim = (d < (u32)wcap) ? d : (u32)wcap;   // fold only final words
            for (u32 w2 = d0; w2 < lim; ++w2)
                sup |= keepAll[w2] & cmask[(size_t)(cbase(w2) + r - 64 * w2)];
            d0 = lim;
            if (d >= (u32)w) break;
            d = __hip_atomic_load(&doneCnt, __ATOMIC_ACQUIRE, __HIP_MEMORY_SCOPE_WORKGROUP);
        }
        if (d > (u32)NW) break;   // early-exit sentinel: output fully determined
        if (w >= 2) sup |= keepAll[w - 2] & dB;
        if (w >= 1) sup |= keepAll[w - 1] & dA;
        // exclusive word solve on wave g: within-word greedy chain
        u64 valw = validm[w];
        u64 cur = valw & ~__ballot(sup != 0ull);
        u64 keptw = 0ull;
        while (cur) {                      // wave-uniform
            int b = __ffsll((long long)cur) - 1;
            keptw |= (1ull << b);
            u64 roww = readlane64(dreg, b);   // row b = whom b suppresses (symmetry)
            cur &= ~(roww | (1ull << b));
        }
        if (lane == 0) {
            keepAll[w] = keptw;
            u32 tk = totK + (u32)__popcll(keptw);
            totK = tk;
            __hip_atomic_store(&doneCnt,
                               (tk >= POST_K) ? (u32)(NW + 9) : (u32)(w + 1),
                               __ATOMIC_RELEASE, __HIP_MEMORY_SCOPE_WORKGROUP);
        }
    }
    __syncthreads();

    // word-prefix ranks
    if (tid == 0) {
        u32 s = 0;
        for (int w = 0; w < NW; ++w) { wpref[w] = s; s += (u32)__popcll(keepAll[w]); }
        wpref[NW] = s;
    }
    __syncthreads();
    u32 totk = wpref[NW]; if (totk > POST_K) totk = POST_K;
    for (int r = tid; r < PRE_K; r += 1024) {
        int w = r >> 6, b = r & 63;
        u64 kw = keepAll[w];
        if ((kw >> b) & 1ull) {
            u32 rank = wpref[w] + (u32)__popcll(kw & ((1ull << b) - 1ull));
            if (rank < POST_K) {
                const float* src = rows + (size_t)r * 16;
                float* dst = out + (size_t)rank * 15;
#pragma unroll
                for (int c = 0; c < 15; ++c) dst[c] = src[c];
            }
        }
    }
    for (int r = (int)totk + tid; r < POST_K; r += 1024) {
        float* dst = out + (size_t)r * 15;
#pragma unroll
        for (int c = 0; c < 15; ++c) dst[c] = 0.f;
    }
}

extern "C" void kernel_launch(void* const* d_in, const int* in_sizes, int n_in,
                              void* d_out, int out_size, void* d_ws, size_t ws_size,
                              hipStream_t stream) {
    const float* loc = (const float*)d_in[0];
    const float2* conf2 = (const float2*)d_in[1];
    const float* lmk = (const float*)d_in[2];
    const float* pri = (const float*)d_in[3];
    const int* imw = (const int*)d_in[4];
    const int* imh = (const int*)d_in[5];
    float* out = (float*)d_out;
    char* base = (char*)d_ws;

    // workspace layout (bytes); total 2,184,768 (< 3,808,896 proven in R3-R11)
    u32* bfill  = (u32*)(base + 32768);     //  32768  (zeroed by histscan)
    u32* bsel   = (u32*)(base + 65536);     //  64     (always written by histscan)
    u64* validm = (u64*)(base + 65600);     //  1024   (zeroed by histscan)
    u32* bstart = (u32*)(base + 67648);     //  32768
    u64* cand   = (u64*)(base + 100416);    //  65536
    float* rows = (float*)(base + 165952);  //  320000 (5000 x 16)
    float4* boxes = (float4*)(base + 485952); // 80896 (NPAD x 16)
    u64* cmask  = (u64*)(base + 566848);    //  1617920 (202240 u64, triangle-packed)

    histscan_kernel<<<1, 1024, 0, stream>>>(conf2, bsel, bstart, bfill, validm);
    compact_kernel<<<(N_IN + 255) / 256, 256, 0, stream>>>(conf2, bsel, bstart, bfill, cand);
    rankdec_kernel<<<24, 256, 0, stream>>>(cand, bstart, bfill, bsel, (const float4*)loc,
                                           (const float4*)pri, lmk, imw, imh,
                                           (float4*)rows, boxes, validm);
    mask_kernel<<<NW * (NW + 1) / 2, 64, 0, stream>>>(boxes, cmask);
    reduce_scatter_kernel<<<1, 1024, 0, stream>>>(cmask, validm, rows, out);
}

// Round 14
// 156.725 us; speedup vs baseline: 1.0631x; 1.0631x over previous
//
#include <hip/hip_runtime.h>
#include <hip/hip_bf16.h>
#include <math.h>

#define N_IN 85680
#define PRE_K 5000
#define POST_K 750
#define NW 79            // ceil(PRE_K/64) words
#define NPAD 5056        // NW*64
#define HSIZE 8192       // linear buckets over score-bit range (0.02, +inf)
#define CAND_MAX 8192
#define CONF_THR 0.02f
#define NMS_THR 0.4f
#define BITS_THR 0x3CA3D70Bu  // bits of smallest float > 0.02f

typedef unsigned int u32;
typedef unsigned long long u64;

// column-major triangle-packed mask: word k's segment starts at cbase(k), holds
// rows 64k..NPAD-1. cbase(k) = k*(5088 - 32k)  [u64 units]; cbase(79)=202240.
__device__ __forceinline__ int cbase(int k) { return k * (5088 - 32 * k); }

// opacity barrier: prevents FMA contraction so f32 math bit-matches numpy ref
__device__ __forceinline__ float opaquef(float x) { asm volatile("" : "+v"(x)); return x; }

// wave-uniform 64-bit broadcast via v_readlane (src lane must be uniform)
__device__ __forceinline__ u64 readlane64(u64 v, int l) {
    u32 lo = __builtin_amdgcn_readlane((u32)v, l);
    u32 hi = __builtin_amdgcn_readlane((u32)(v >> 32), l);
    return ((u64)hi << 32) | (u64)lo;
}

// monotone bucket of a score's float bits (score > CONF_THR guaranteed)
__device__ __forceinline__ u32 bucket_of(u32 bits) {
    u32 b = (bits - BITS_THR) >> 13;
    return b >= HSIZE ? (HSIZE - 1) : b;
}

// ---------------- histogram of valid score buckets (multi-block) ----------------
__global__ __launch_bounds__(256) void hist_kernel(const float2* __restrict__ conf2,
                                                   u32* __restrict__ hist) {
    __shared__ u32 h[HSIZE];
    for (int b = threadIdx.x; b < HSIZE; b += 256) h[b] = 0u;
    __syncthreads();
    int i = blockIdx.x * 256 + threadIdx.x;
    if (i < N_IN) {
        float s = conf2[i].y;
        if (s > CONF_THR) atomicAdd(&h[bucket_of(__float_as_uint(s))], 1u);
    }
    __syncthreads();
    for (int b = threadIdx.x; b < HSIZE; b += 256) {
        u32 v = h[b];
        if (v) atomicAdd(&hist[b], v);
    }
}

// ---------------- suffix-scan: bstart[b] = #keys in buckets > b; bsel ----------------
__global__ __launch_bounds__(1024) void scan_kernel(const u32* __restrict__ hist,
                                                    u32* __restrict__ bsel,
                                                    u32* __restrict__ bstart) {
    __shared__ u32 tot[1024];
    int c = threadIdx.x;
    u32 lh[8];
    u32 t = 0;
#pragma unroll
    for (int k = 0; k < 8; ++k) { lh[k] = hist[c * 8 + k]; t += lh[k]; }
    tot[c] = t;
    __syncthreads();
    for (int d = 1; d < 1024; d <<= 1) {
        u32 v = tot[c] + ((c + d < 1024) ? tot[c + d] : 0u);
        __syncthreads();
        tot[c] = v;
        __syncthreads();
    }
    u32 above = (c + 1 < 1024) ? tot[c + 1] : 0u;
    u32 s = above;
    for (int k = 7; k >= 0; --k) { bstart[c * 8 + k] = s; s += lh[k]; }
    if (above < PRE_K && above + t >= PRE_K) {
        u32 cum = above;
        for (int k = 7; k >= 0; --k) {
            cum += lh[k];
            if (cum >= PRE_K) { bsel[0] = (u32)(c * 8 + k); break; }
        }
    }
    if (c == 0 && tot[0] < PRE_K) bsel[0] = 0u;
}

// ---------------- scatter candidates bucket-grouped ----------------
__global__ __launch_bounds__(256) void compact_kernel(const float2* __restrict__ conf2,
                                                      const u32* __restrict__ bsel,
                                                      const u32* __restrict__ bstart,
                                                      u32* __restrict__ bfill,
                                                      u64* __restrict__ cand) {
    int i = blockIdx.x * 256 + threadIdx.x;
    if (i >= N_IN) return;
    float sc = conf2[i].y;
    if (!(sc > CONF_THR)) return;
    u32 bits = __float_as_uint(sc);
    u32 b = bucket_of(bits);
    if (b < bsel[0]) return;
    u32 pos = bstart[b] + atomicAdd(&bfill[b], 1u);
    if (pos < CAND_MAX) cand[pos] = ((u64)bits << 32) | (u64)(u32)(~(u32)i);
}

// ---------------- fused: exact rank within bucket + decode -> rows/boxes/validm ----------------
__global__ __launch_bounds__(256) void rankdec_kernel(const u64* __restrict__ cand,
                                                      const u32* __restrict__ bstart,
                                                      const u32* __restrict__ bfill,
                                                      const u32* __restrict__ bsel,
                                                      const float4* __restrict__ loc4,
                                                      const float4* __restrict__ pri4,
                                                      const float* __restrict__ lmk,
                                                      const int* __restrict__ imw,
                                                      const int* __restrict__ imh,
                                                      float4* __restrict__ rows4,
                                                      float4* __restrict__ boxes,
                                                      u64* __restrict__ validm) {
    u32 bs = bsel[0];
    u32 total = bstart[bs] + bfill[bs];
    if (total > CAND_MAX) total = CAND_MAX;
    float W = (float)(*imw), H = (float)(*imh);
    for (u32 s = blockIdx.x * blockDim.x + threadIdx.x; s < total;
         s += gridDim.x * blockDim.x) {
        u64 key = cand[s];
        u32 b = bucket_of((u32)(key >> 32));
        u32 st = bstart[b];
        u32 en = st + bfill[b];
        if (en > CAND_MAX) en = CAND_MAX;
        u32 r = st;
        for (u32 j = st; j < en; ++j) r += (cand[j] > key) ? 1u : 0u;
        if (r >= PRE_K) continue;
        u32 i = ~(u32)key;
        float score = __uint_as_float((u32)(key >> 32));
        float4 L = loc4[i];
        float4 P = pri4[i];
        float cx = P.x + opaquef((L.x * 0.1f) * P.z);
        float cy = P.y + opaquef((L.y * 0.1f) * P.w);
        float bw = P.z * (float)exp((double)(L.z * 0.2f));
        float bh = P.w * (float)exp((double)(L.w * 0.2f));
        float hw = opaquef(bw * 0.5f), hh = opaquef(bh * 0.5f);
        float x0 = (cx - hw) * W, y0 = (cy - hh) * H;
        float x1 = (cx + hw) * W, y1 = (cy + hh) * H;
        boxes[r] = make_float4(x0, y0, x1, y1);
        float lm[10];
#pragma unroll
        for (int p = 0; p < 5; ++p) {
            float2 q = ((const float2*)lmk)[(size_t)i * 5 + p];
            lm[2 * p]     = (P.x + opaquef((q.x * 0.1f) * P.z)) * W;
            lm[2 * p + 1] = (P.y + opaquef((q.y * 0.1f) * P.w)) * H;
        }
        float4* row = rows4 + (size_t)r * 4;
        row[0] = make_float4(x0, y0, x1, y1);
        row[1] = make_float4(score, lm[0], lm[1], lm[2]);
        row[2] = make_float4(lm[3], lm[4], lm[5], lm[6]);
        row[3] = make_float4(lm[7], lm[8], lm[9], 0.f);
        atomicOr(&validm[r >> 6], 1ull << (r & 63));
    }
}

// ---------------- symmetric IoU bitmask, column-major triangle-packed ----------------
__global__ __launch_bounds__(64) void mask_kernel(const float4* __restrict__ boxes,
                                                  u64* __restrict__ cmask) {
    int rem = blockIdx.x, rc = 0;
    while (rem >= rc + 1) { rem -= rc + 1; ++rc; }
    int cc = rem;
    __shared__ float4 cb[64];
    int t = threadIdx.x;
    cb[t] = boxes[cc * 64 + t];
    int i = rc * 64 + t;
    float4 bi = boxes[i];
    __syncthreads();
    float areai = (bi.z - bi.x) * (bi.w - bi.y);
    u64 word = 0ull;
#pragma unroll 4
    for (int k = 0; k < 64; ++k) {
        float4 bj = cb[k];
        float areaj = (bj.z - bj.x) * (bj.w - bj.y);
        float ltx = fmaxf(bi.x, bj.x), lty = fmaxf(bi.y, bj.y);
        float rbx = fminf(bi.z, bj.z), rby = fminf(bi.w, bj.w);
        float wx = fmaxf(rbx - ltx, 0.f), wy = fmaxf(rby - lty, 0.f);
        float inter = opaquef(wx * wy);
        float uni = fmaxf(areai + areaj - inter, 1e-12f);
        float iou = inter / uni;
        if (iou > NMS_THR) word |= (1ull << k);
    }
    if (i < PRE_K) cmask[(size_t)(cbase(cc) + (i - 64 * cc))] = word;
}

// ---------------- exact one-pass Gauss-Seidel NMS + fused scatter (1 block, 16 waves) ----
// v3: per-word done[] flags (release/acquire, spread addresses + s_sleep backoff);
// predecessor-column folds are PIPELINED 8-wide register batches issued BEFORE
// the flag wait (column data is static — only the AND needs keepAll final), so
// fold latency rides under spin time instead of serializing the release chain.
// Early-exit via sticky fin flag: post-750 words write zero keeps (rank-safe).
__global__ __launch_bounds__(1024) void reduce_scatter_kernel(const u64* __restrict__ cmask,
                                                              const u64* __restrict__ validm,
                                                              const float* __restrict__ rows,
                                                              float* __restrict__ out) {
    int tid = threadIdx.x;
    int g = tid >> 6, lane = tid & 63;
    __shared__ u64 keepAll[96];
    __shared__ u32 done[96];
    __shared__ u32 totKs[96];
    __shared__ u32 finf;
    __shared__ u32 wpref[96];
    for (int k = tid; k < 96; k += 1024) { keepAll[k] = 0ull; done[k] = 0u; }
    if (tid == 0) finf = 0u;
    __syncthreads();

    for (int s = 0; s < 5; ++s) {
        int w = s * 16 + g;
        if (w >= NW) break;
        int r = 64 * w + lane;
        u64 dreg = cmask[(size_t)(cbase(w) + lane)];   // UNMASKED (R13 fix)
        u64 dA = (w >= 1) ? cmask[(size_t)(cbase(w - 1) + r - 64 * (w - 1))] : 0ull;
        u64 dB = (w >= 2) ? cmask[(size_t)(cbase(w - 2) + r - 64 * (w - 2))] : 0ull;
        int wcap = (w >= 2) ? (w - 2) : 0;
        u64 sup = 0ull;
        bool dead = false;

        // pipelined fold over predecessor words [0, wcap): 8-wide double-buffered
        u64 c[8], n[8];
        int d0 = 0;
        int nb = wcap < 8 ? wcap : 8;
#pragma unroll
        for (int j = 0; j < 8; ++j)
            c[j] = (j < nb) ? cmask[(size_t)(cbase(j) + r - 64 * j)] : 0ull;
        while (d0 < wcap) {
            int d1 = d0 + nb;
            int nb2 = wcap - d1; if (nb2 > 8) nb2 = 8;
#pragma unroll
            for (int j = 0; j < 8; ++j)
                n[j] = (j < nb2) ? cmask[(size_t)(cbase(d1 + j) + r - 64 * (d1 + j))] : 0ull;
            for (;;) {   // wait for this batch's flags (d0+nb-1 <= w-3: no deadlock)
                if (__hip_atomic_load(&finf, __ATOMIC_ACQUIRE, __HIP_MEMORY_SCOPE_WORKGROUP)) { dead = true; break; }
                if (__hip_atomic_load(&done[d0 + nb - 1], __ATOMIC_ACQUIRE, __HIP_MEMORY_SCOPE_WORKGROUP)) break;
                __builtin_amdgcn_s_sleep(1);
            }
            if (dead) break;
#pragma unroll
            for (int j = 0; j < 8; ++j) if (j < nb) sup |= keepAll[d0 + j] & c[j];
#pragma unroll
            for (int j = 0; j < 8; ++j) c[j] = n[j];
            d0 = d1; nb = nb2;
        }
        // final handshake on word w-1
        if (!dead && w > 0) {
            for (;;) {
                if (__hip_atomic_load(&finf, __ATOMIC_ACQUIRE, __HIP_MEMORY_SCOPE_WORKGROUP)) { dead = true; break; }
                if (__hip_atomic_load(&done[w - 1], __ATOMIC_ACQUIRE, __HIP_MEMORY_SCOPE_WORKGROUP)) break;
                __builtin_amdgcn_s_sleep(1);
            }
        }
        u64 keptw = 0ull;
        u32 tp = 0u;
        if (!dead) {
            tp = (w > 0) ? totKs[w - 1] : 0u;
            if (tp < POST_K) {
                if (w >= 2) sup |= keepAll[w - 2] & dB;
                if (w >= 1) sup |= keepAll[w - 1] & dA;
                u64 valw = validm[w];
                u64 cur = valw & ~__ballot(sup != 0ull);
                while (cur) {                  // wave-uniform chain
                    int b = __ffsll((long long)cur) - 1;
                    keptw |= (1ull << b);
                    u64 roww = readlane64(dreg, b);  // row b = whom b suppresses
                    cur &= ~(roww | (1ull << b));
                }
            }
        }
        if (lane == 0) {
            keepAll[w] = keptw;                // 0 when dead/past-750 (rank-safe)
            u32 tk = tp + (u32)__popcll(keptw);
            totKs[w] = tk;
            if (tk >= POST_K && !dead)
                __hip_atomic_store(&finf, 1u, __ATOMIC_RELEASE, __HIP_MEMORY_SCOPE_WORKGROUP);
            __hip_atomic_store(&done[w], 1u, __ATOMIC_RELEASE, __HIP_MEMORY_SCOPE_WORKGROUP);
        }
    }
    __syncthreads();

    // word-prefix ranks
    if (tid == 0) {
        u32 s = 0;
        for (int w = 0; w < NW; ++w) { wpref[w] = s; s += (u32)__popcll(keepAll[w]); }
        wpref[NW] = s;
    }
    __syncthreads();
    u32 totk = wpref[NW]; if (totk > POST_K) totk = POST_K;
    for (int r = tid; r < PRE_K; r += 1024) {
        int w = r >> 6, b = r & 63;
        u64 kw = keepAll[w];
        if ((kw >> b) & 1ull) {
            u32 rank = wpref[w] + (u32)__popcll(kw & ((1ull << b) - 1ull));
            if (rank < POST_K) {
                const float* src = rows + (size_t)r * 16;
                float* dst = out + (size_t)rank * 15;
#pragma unroll
                for (int c2 = 0; c2 < 15; ++c2) dst[c2] = src[c2];
            }
        }
    }
    for (int r = (int)totk + tid; r < POST_K; r += 1024) {
        float* dst = out + (size_t)r * 15;
#pragma unroll
        for (int c2 = 0; c2 < 15; ++c2) dst[c2] = 0.f;
    }
}

extern "C" void kernel_launch(void* const* d_in, const int* in_sizes, int n_in,
                              void* d_out, int out_size, void* d_ws, size_t ws_size,
                              hipStream_t stream) {
    const float* loc = (const float*)d_in[0];
    const float2* conf2 = (const float2*)d_in[1];
    const float* lmk = (const float*)d_in[2];
    const float* pri = (const float*)d_in[3];
    const int* imw = (const int*)d_in[4];
    const int* imh = (const int*)d_in[5];
    float* out = (float*)d_out;
    char* base = (char*)d_ws;

    // workspace layout (bytes); total 2,184,768 (< 3,808,896 proven in R3-R13)
    u32* hist   = (u32*)(base + 0);         //  32768  [zeroed by memset]
    u32* bfill  = (u32*)(base + 32768);     //  32768  [zeroed]
    u32* bsel   = (u32*)(base + 65536);     //  64     [zeroed]
    u64* validm = (u64*)(base + 65600);     //  1024   [zeroed]  -> zero [0,66624)
    u32* bstart = (u32*)(base + 67648);     //  32768
    u64* cand   = (u64*)(base + 100416);    //  65536
    float* rows = (float*)(base + 165952);  //  320000 (5000 x 16)
    float4* boxes = (float4*)(base + 485952); // 80896 (NPAD x 16)
    u64* cmask  = (u64*)(base + 566848);    //  1617920 (202240 u64, triangle-packed)

    hipMemsetAsync(d_ws, 0, 66624, stream);

    hist_kernel<<<(N_IN + 255) / 256, 256, 0, stream>>>(conf2, hist);
    scan_kernel<<<1, 1024, 0, stream>>>(hist, bsel, bstart);
    compact_kernel<<<(N_IN + 255) / 256, 256, 0, stream>>>(conf2, bsel, bstart, bfill, cand);
    rankdec_kernel<<<24, 256, 0, stream>>>(cand, bstart, bfill, bsel, (const float4*)loc,
                                           (const float4*)pri, lmk, imw, imh,
                                           (float4*)rows, boxes, validm);
    mask_kernel<<<NW * (NW + 1) / 2, 64, 0, stream>>>(boxes, cmask);
    reduce_scatter_kernel<<<1, 1024, 0, stream>>>(cmask, validm, rows, out);
}

// Round 15
// 153.641 us; speedup vs baseline: 1.0845x; 1.0201x over previous
//
#include <hip/hip_runtime.h>
#include <hip/hip_bf16.h>
#include <math.h>

#define N_IN 85680
#define PRE_K 5000
#define POST_K 750
#define NW 79            // ceil(PRE_K/64) words
#define NPAD 5056        // NW*64
#define HSIZE 8192       // linear buckets over score-bit range (0.02, +inf)
#define CAND_MAX 8192
#define CONF_THR 0.02f
#define NMS_THR 0.4f
#define BITS_THR 0x3CA3D70Bu  // bits of smallest float > 0.02f

typedef unsigned int u32;
typedef unsigned long long u64;

// column-major triangle-packed mask: word k's segment starts at cbase(k), holds
// rows 64k..NPAD-1. cbase(k) = k*(5088 - 32k)  [u64 units]; cbase(79)=202240.
__device__ __forceinline__ int cbase(int k) { return k * (5088 - 32 * k); }

// opacity barrier: prevents FMA contraction so f32 math bit-matches numpy ref
__device__ __forceinline__ float opaquef(float x) { asm volatile("" : "+v"(x)); return x; }

// wave-uniform 64-bit broadcast via v_readlane (src lane must be uniform)
__device__ __forceinline__ u64 readlane64(u64 v, int l) {
    u32 lo = __builtin_amdgcn_readlane((u32)v, l);
    u32 hi = __builtin_amdgcn_readlane((u32)(v >> 32), l);
    return ((u64)hi << 32) | (u64)lo;
}

// monotone bucket of a score's float bits (score > CONF_THR guaranteed)
__device__ __forceinline__ u32 bucket_of(u32 bits) {
    u32 b = (bits - BITS_THR) >> 13;
    return b >= HSIZE ? (HSIZE - 1) : b;
}

// ---------------- histogram of valid score buckets (multi-block) ----------------
__global__ __launch_bounds__(256) void hist_kernel(const float2* __restrict__ conf2,
                                                   u32* __restrict__ hist) {
    __shared__ u32 h[HSIZE];
    for (int b = threadIdx.x; b < HSIZE; b += 256) h[b] = 0u;
    __syncthreads();
    int i = blockIdx.x * 256 + threadIdx.x;
    if (i < N_IN) {
        float s = conf2[i].y;
        if (s > CONF_THR) atomicAdd(&h[bucket_of(__float_as_uint(s))], 1u);
    }
    __syncthreads();
    for (int b = threadIdx.x; b < HSIZE; b += 256) {
        u32 v = h[b];
        if (v) atomicAdd(&hist[b], v);
    }
}

// ---------------- suffix-scan: bstart[b] = #keys in buckets > b; bsel ----------------
__global__ __launch_bounds__(1024) void scan_kernel(const u32* __restrict__ hist,
                                                    u32* __restrict__ bsel,
                                                    u32* __restrict__ bstart) {
    __shared__ u32 tot[1024];
    int c = threadIdx.x;
    u32 lh[8];
    u32 t = 0;
#pragma unroll
    for (int k = 0; k < 8; ++k) { lh[k] = hist[c * 8 + k]; t += lh[k]; }
    tot[c] = t;
    __syncthreads();
    for (int d = 1; d < 1024; d <<= 1) {
        u32 v = tot[c] + ((c + d < 1024) ? tot[c + d] : 0u);
        __syncthreads();
        tot[c] = v;
        __syncthreads();
    }
    u32 above = (c + 1 < 1024) ? tot[c + 1] : 0u;
    u32 s = above;
    for (int k = 7; k >= 0; --k) { bstart[c * 8 + k] = s; s += lh[k]; }
    if (above < PRE_K && above + t >= PRE_K) {
        u32 cum = above;
        for (int k = 7; k >= 0; --k) {
            cum += lh[k];
            if (cum >= PRE_K) { bsel[0] = (u32)(c * 8 + k); break; }
        }
    }
    if (c == 0 && tot[0] < PRE_K) bsel[0] = 0u;
}

// ---------------- scatter candidates bucket-grouped ----------------
__global__ __launch_bounds__(256) void compact_kernel(const float2* __restrict__ conf2,
                                                      const u32* __restrict__ bsel,
                                                      const u32* __restrict__ bstart,
                                                      u32* __restrict__ bfill,
                                                      u64* __restrict__ cand) {
    int i = blockIdx.x * 256 + threadIdx.x;
    if (i >= N_IN) return;
    float sc = conf2[i].y;
    if (!(sc > CONF_THR)) return;
    u32 bits = __float_as_uint(sc);
    u32 b = bucket_of(bits);
    if (b < bsel[0]) return;
    u32 pos = bstart[b] + atomicAdd(&bfill[b], 1u);
    if (pos < CAND_MAX) cand[pos] = ((u64)bits << 32) | (u64)(u32)(~(u32)i);
}

// ---------------- fused: exact rank within bucket + decode -> rows/boxes/validm ----------------
__global__ __launch_bounds__(256) void rankdec_kernel(const u64* __restrict__ cand,
                                                      const u32* __restrict__ bstart,
                                                      const u32* __restrict__ bfill,
                                                      const u32* __restrict__ bsel,
                                                      const float4* __restrict__ loc4,
                                                      const float4* __restrict__ pri4,
                                                      const float* __restrict__ lmk,
                                                      const int* __restrict__ imw,
                                                      const int* __restrict__ imh,
                                                      float4* __restrict__ rows4,
                                                      float4* __restrict__ boxes,
                                                      u64* __restrict__ validm) {
    u32 bs = bsel[0];
    u32 total = bstart[bs] + bfill[bs];
    if (total > CAND_MAX) total = CAND_MAX;
    float W = (float)(*imw), H = (float)(*imh);
    for (u32 s = blockIdx.x * blockDim.x + threadIdx.x; s < total;
         s += gridDim.x * blockDim.x) {
        u64 key = cand[s];
        u32 b = bucket_of((u32)(key >> 32));
        u32 st = bstart[b];
        u32 en = st + bfill[b];
        if (en > CAND_MAX) en = CAND_MAX;
        u32 r = st;
        for (u32 j = st; j < en; ++j) r += (cand[j] > key) ? 1u : 0u;
        if (r >= PRE_K) continue;
        u32 i = ~(u32)key;
        float score = __uint_as_float((u32)(key >> 32));
        float4 L = loc4[i];
        float4 P = pri4[i];
        float cx = P.x + opaquef((L.x * 0.1f) * P.z);
        float cy = P.y + opaquef((L.y * 0.1f) * P.w);
        float bw = P.z * (float)exp((double)(L.z * 0.2f));
        float bh = P.w * (float)exp((double)(L.w * 0.2f));
        float hw = opaquef(bw * 0.5f), hh = opaquef(bh * 0.5f);
        float x0 = (cx - hw) * W, y0 = (cy - hh) * H;
        float x1 = (cx + hw) * W, y1 = (cy + hh) * H;
        boxes[r] = make_float4(x0, y0, x1, y1);
        float lm[10];
#pragma unroll
        for (int p = 0; p < 5; ++p) {
            float2 q = ((const float2*)lmk)[(size_t)i * 5 + p];
            lm[2 * p]     = (P.x + opaquef((q.x * 0.1f) * P.z)) * W;
            lm[2 * p + 1] = (P.y + opaquef((q.y * 0.1f) * P.w)) * H;
        }
        float4* row = rows4 + (size_t)r * 4;
        row[0] = make_float4(x0, y0, x1, y1);
        row[1] = make_float4(score, lm[0], lm[1], lm[2]);
        row[2] = make_float4(lm[3], lm[4], lm[5], lm[6]);
        row[3] = make_float4(lm[7], lm[8], lm[9], 0.f);
        atomicOr(&validm[r >> 6], 1ull << (r & 63));
    }
}

// ---------------- symmetric IoU bitmask, column-major triangle-packed ----------------
__global__ __launch_bounds__(64) void mask_kernel(const float4* __restrict__ boxes,
                                                  u64* __restrict__ cmask) {
    int rem = blockIdx.x, rc = 0;
    while (rem >= rc + 1) { rem -= rc + 1; ++rc; }
    int cc = rem;
    __shared__ float4 cb[64];
    int t = threadIdx.x;
    cb[t] = boxes[cc * 64 + t];
    int i = rc * 64 + t;
    float4 bi = boxes[i];
    __syncthreads();
    float areai = (bi.z - bi.x) * (bi.w - bi.y);
    u64 word = 0ull;
#pragma unroll 4
    for (int k = 0; k < 64; ++k) {
        float4 bj = cb[k];
        float areaj = (bj.z - bj.x) * (bj.w - bj.y);
        float ltx = fmaxf(bi.x, bj.x), lty = fmaxf(bi.y, bj.y);
        float rbx = fminf(bi.z, bj.z), rby = fminf(bi.w, bj.w);
        float wx = fmaxf(rbx - ltx, 0.f), wy = fmaxf(rby - lty, 0.f);
        float inter = opaquef(wx * wy);
        float uni = fmaxf(areai + areaj - inter, 1e-12f);
        float iou = inter / uni;
        if (iou > NMS_THR) word |= (1ull << k);
    }
    if (i < PRE_K) cmask[(size_t)(cbase(cc) + (i - 64 * cc))] = word;
}

// guarded coalesced column load for the fold pipeline
#define LDCOL(j, base, cnt) \
    (((j) < (cnt)) ? cmask[(size_t)(cbase((base) + (j)) + r - 64 * ((base) + (j)))] : 0ull)

// ---------------- exact one-pass Gauss-Seidel NMS + fused scatter (1 block, 8 waves) ----
// v4: 512 threads => 128-VGPR budget so the 8-wide double-buffered fold lives in
// NAMED registers c0..c7/n0..n7 (R14's c[8]/n[8] arrays spilled to scratch at the
// 1024-thread 64-VGPR cap, putting ~600cy scratch round-trips on the release
// chain). Per-word done[] flags, register-bridged dA/dB, sticky finf early-exit.
__global__ __launch_bounds__(512) void reduce_scatter_kernel(const u64* __restrict__ cmask,
                                                             const u64* __restrict__ validm,
                                                             const float* __restrict__ rows,
                                                             float* __restrict__ out) {
    int tid = threadIdx.x;
    int g = tid >> 6, lane = tid & 63;
    __shared__ u64 keepAll[96];
    __shared__ u32 done[96];
    __shared__ u32 totKs[96];
    __shared__ u32 finf;
    __shared__ u32 wpref[96];
    for (int k = tid; k < 96; k += 512) { keepAll[k] = 0ull; done[k] = 0u; }
    if (tid == 0) finf = 0u;
    __syncthreads();

    for (int s = 0; s < 10; ++s) {
        int w = s * 8 + g;
        if (w >= NW) break;
        int r = 64 * w + lane;
        u64 dreg = cmask[(size_t)(cbase(w) + lane)];   // UNMASKED (R13 fix)
        u64 dA = (w >= 1) ? cmask[(size_t)(cbase(w - 1) + r - 64 * (w - 1))] : 0ull;
        u64 dB = (w >= 2) ? cmask[(size_t)(cbase(w - 2) + r - 64 * (w - 2))] : 0ull;
        int wcap = (w >= 2) ? (w - 2) : 0;
        u64 sup = 0ull;
        bool dead = false;

        // pipelined fold over predecessor words [0, wcap): 8-wide double-buffered,
        // individually named registers (no arrays -> no scratch spill)
        int d0 = 0;
        int nb = wcap < 8 ? wcap : 8;
        u64 c0 = LDCOL(0, 0, nb), c1 = LDCOL(1, 0, nb), c2 = LDCOL(2, 0, nb), c3 = LDCOL(3, 0, nb);
        u64 c4 = LDCOL(4, 0, nb), c5 = LDCOL(5, 0, nb), c6 = LDCOL(6, 0, nb), c7 = LDCOL(7, 0, nb);
        while (d0 < wcap) {
            int d1 = d0 + nb;
            int nb2 = wcap - d1; if (nb2 > 8) nb2 = 8;
            u64 n0 = LDCOL(0, d1, nb2), n1 = LDCOL(1, d1, nb2), n2 = LDCOL(2, d1, nb2), n3 = LDCOL(3, d1, nb2);
            u64 n4 = LDCOL(4, d1, nb2), n5 = LDCOL(5, d1, nb2), n6 = LDCOL(6, d1, nb2), n7 = LDCOL(7, d1, nb2);
            for (;;) {   // wait for this batch's flags (d0+nb-1 <= w-3: no deadlock)
                if (__hip_atomic_load(&finf, __ATOMIC_ACQUIRE, __HIP_MEMORY_SCOPE_WORKGROUP)) { dead = true; break; }
                if (__hip_atomic_load(&done[d0 + nb - 1], __ATOMIC_ACQUIRE, __HIP_MEMORY_SCOPE_WORKGROUP)) break;
                __builtin_amdgcn_s_sleep(1);
            }
            if (dead) break;
            if (0 < nb) sup |= keepAll[d0 + 0] & c0;
            if (1 < nb) sup |= keepAll[d0 + 1] & c1;
            if (2 < nb) sup |= keepAll[d0 + 2] & c2;
            if (3 < nb) sup |= keepAll[d0 + 3] & c3;
            if (4 < nb) sup |= keepAll[d0 + 4] & c4;
            if (5 < nb) sup |= keepAll[d0 + 5] & c5;
            if (6 < nb) sup |= keepAll[d0 + 6] & c6;
            if (7 < nb) sup |= keepAll[d0 + 7] & c7;
            c0 = n0; c1 = n1; c2 = n2; c3 = n3; c4 = n4; c5 = n5; c6 = n6; c7 = n7;
            d0 = d1; nb = nb2;
        }
        // final handshake on word w-1
        if (!dead && w > 0) {
            for (;;) {
                if (__hip_atomic_load(&finf, __ATOMIC_ACQUIRE, __HIP_MEMORY_SCOPE_WORKGROUP)) { dead = true; break; }
                if (__hip_atomic_load(&done[w - 1], __ATOMIC_ACQUIRE, __HIP_MEMORY_SCOPE_WORKGROUP)) break;
                __builtin_amdgcn_s_sleep(1);
            }
        }
        u64 keptw = 0ull;
        u32 tp = 0u;
        if (!dead) {
            tp = (w > 0) ? totKs[w - 1] : 0u;
            if (tp < POST_K) {
                if (w >= 2) sup |= keepAll[w - 2] & dB;
                if (w >= 1) sup |= keepAll[w - 1] & dA;
                u64 valw = validm[w];
                u64 cur = valw & ~__ballot(sup != 0ull);
                while (cur) {                  // wave-uniform chain (short: kept sparse)
                    int b = __ffsll((long long)cur) - 1;
                    keptw |= (1ull << b);
                    u64 roww = readlane64(dreg, b);  // row b = whom b suppresses
                    cur &= ~(roww | (1ull << b));
                }
            }
        }
        if (lane == 0) {
            keepAll[w] = keptw;                // 0 when dead/past-750 (rank-safe)
            u32 tk = tp + (u32)__popcll(keptw);
            totKs[w] = tk;
            if (tk >= POST_K && !dead)
                __hip_atomic_store(&finf, 1u, __ATOMIC_RELEASE, __HIP_MEMORY_SCOPE_WORKGROUP);
            __hip_atomic_store(&done[w], 1u, __ATOMIC_RELEASE, __HIP_MEMORY_SCOPE_WORKGROUP);
        }
    }
    __syncthreads();

    // word-prefix ranks
    if (tid == 0) {
        u32 s = 0;
        for (int w = 0; w < NW; ++w) { wpref[w] = s; s += (u32)__popcll(keepAll[w]); }
        wpref[NW] = s;
    }
    __syncthreads();
    u32 totk = wpref[NW]; if (totk > POST_K) totk = POST_K;
    for (int r = tid; r < PRE_K; r += 512) {
        int w = r >> 6, b = r & 63;
        u64 kw = keepAll[w];
        if ((kw >> b) & 1ull) {
            u32 rank = wpref[w] + (u32)__popcll(kw & ((1ull << b) - 1ull));
            if (rank < POST_K) {
                const float* src = rows + (size_t)r * 16;
                float* dst = out + (size_t)rank * 15;
#pragma unroll
                for (int c2 = 0; c2 < 15; ++c2) dst[c2] = src[c2];
            }
        }
    }
    for (int r = (int)totk + tid; r < POST_K; r += 512) {
        float* dst = out + (size_t)r * 15;
#pragma unroll
        for (int c2 = 0; c2 < 15; ++c2) dst[c2] = 0.f;
    }
}

extern "C" void kernel_launch(void* const* d_in, const int* in_sizes, int n_in,
                              void* d_out, int out_size, void* d_ws, size_t ws_size,
                              hipStream_t stream) {
    const float* loc = (const float*)d_in[0];
    const float2* conf2 = (const float2*)d_in[1];
    const float* lmk = (const float*)d_in[2];
    const float* pri = (const float*)d_in[3];
    const int* imw = (const int*)d_in[4];
    const int* imh = (const int*)d_in[5];
    float* out = (float*)d_out;
    char* base = (char*)d_ws;

    // workspace layout (bytes); total 2,184,768 (< 3,808,896 proven in R3-R14)
    u32* hist   = (u32*)(base + 0);         //  32768  [zeroed by memset]
    u32* bfill  = (u32*)(base + 32768);     //  32768  [zeroed]
    u32* bsel   = (u32*)(base + 65536);     //  64     [zeroed]
    u64* validm = (u64*)(base + 65600);     //  1024   [zeroed]  -> zero [0,66624)
    u32* bstart = (u32*)(base + 67648);     //  32768
    u64* cand   = (u64*)(base + 100416);    //  65536
    float* rows = (float*)(base + 165952);  //  320000 (5000 x 16)
    float4* boxes = (float4*)(base + 485952); // 80896 (NPAD x 16)
    u64* cmask  = (u64*)(base + 566848);    //  1617920 (202240 u64, triangle-packed)

    hipMemsetAsync(d_ws, 0, 66624, stream);

    hist_kernel<<<(N_IN + 255) / 256, 256, 0, stream>>>(conf2, hist);
    scan_kernel<<<1, 1024, 0, stream>>>(hist, bsel, bstart);
    compact_kernel<<<(N_IN + 255) / 256, 256, 0, stream>>>(conf2, bsel, bstart, bfill, cand);
    rankdec_kernel<<<24, 256, 0, stream>>>(cand, bstart, bfill, bsel, (const float4*)loc,
                                           (const float4*)pri, lmk, imw, imh,
                                           (float4*)rows, boxes, validm);
    mask_kernel<<<NW * (NW + 1) / 2, 64, 0, stream>>>(boxes, cmask);
    reduce_scatter_kernel<<<1, 512, 0, stream>>>(cmask, validm, rows, out);
}